// Round 1
// baseline (4262.712 us; speedup 1.0000x reference)
//
#include <hip/hip_runtime.h>
#include <math.h>

#define TT 12
#define NN 20000
#define EE 320000

__device__ __forceinline__ float dot4(float4 a, float4 b) {
    return a.x * b.x + a.y * b.y + a.z * b.z + a.w * b.w;
}

__device__ __forceinline__ float wsum64(float v) {
#pragma unroll
    for (int o = 32; o >= 1; o >>= 1) v += __shfl_xor(v, o);
    return v;
}

// ---------------- weight transpose (once per launch) ----------------
// WT layout (floats): WqT@0, WkT@4096, WvT@8192, WoT@12288,
// CzT@16384, DzT@20480, CrT@24576, DrT@28672, ChT@32768, DhT@36864,
// W1T@40960 (256x64), W2T@57344 (64x256)
__global__ void k_transpose(const float* __restrict__ Wq, const float* __restrict__ Wk,
                            const float* __restrict__ Wv, const float* __restrict__ Wo,
                            const float* __restrict__ Cz, const float* __restrict__ Dz,
                            const float* __restrict__ Cr, const float* __restrict__ Dr,
                            const float* __restrict__ Ch, const float* __restrict__ Dh,
                            const float* __restrict__ W1, const float* __restrict__ W2,
                            float* __restrict__ WT) {
    int tid = blockIdx.x * 256 + threadIdx.x;
    if (tid < 40960) {
        int m = tid >> 12, r = tid & 4095;
        int i = r >> 6, j = r & 63;
        const float* src;
        switch (m) {
            case 0: src = Wq; break; case 1: src = Wk; break;
            case 2: src = Wv; break; case 3: src = Wo; break;
            case 4: src = Cz; break; case 5: src = Dz; break;
            case 6: src = Cr; break; case 7: src = Dr; break;
            case 8: src = Ch; break; default: src = Dh; break;
        }
        WT[m * 4096 + j * 64 + i] = src[i * 64 + j];
    } else if (tid < 40960 + 16384) {
        int r = tid - 40960;
        int i = r >> 8, j = r & 255;            // W1 is (64,256)
        WT[40960 + j * 64 + i] = W1[i * 256 + j];
    } else if (tid < 73728) {
        int r = tid - 57344;
        int k = r >> 6, d = r & 63;             // W2 is (256,64)
        WT[57344 + d * 256 + k] = W2[k * 64 + d];
    }
}

// ---------------- CSR build ----------------
__global__ void k_zero_offs(int* __restrict__ offs) {
    int i = blockIdx.x * 256 + threadIdx.x;
    if (i < NN + 1) offs[i] = 0;
}
__global__ void k_count(const int* __restrict__ dst, int* __restrict__ offs) {
    int e = blockIdx.x * 256 + threadIdx.x;
    if (e < EE) atomicAdd(&offs[dst[e] + 1], 1);
}
__global__ void k_scan(int* __restrict__ offs, int* __restrict__ cur) {
    __shared__ int buf[1024];
    __shared__ int carry;
    int tid = threadIdx.x;
    if (tid == 0) carry = 0;
    __syncthreads();
    const int total = NN + 1;
    for (int base = 0; base < total; base += 1024) {
        int idx = base + tid;
        int v = (idx < total) ? offs[idx] : 0;
        buf[tid] = v;
        __syncthreads();
        for (int o = 1; o < 1024; o <<= 1) {
            int t = (tid >= o) ? buf[tid - o] : 0;
            __syncthreads();
            buf[tid] += t;
            __syncthreads();
        }
        int incl = buf[tid] + carry;
        if (idx < total) offs[idx] = incl;
        __syncthreads();
        if (tid == 1023) carry += buf[1023];
        __syncthreads();
    }
    for (int i = tid; i < NN; i += 1024) cur[i] = offs[i];
}
__global__ void k_fill(const int* __restrict__ src, const int* __restrict__ dst,
                       const float* __restrict__ w, int* __restrict__ cur,
                       int* __restrict__ esrc, float* __restrict__ ews) {
    int e = blockIdx.x * 256 + threadIdx.x;
    if (e < EE) {
        int dn = dst[e];
        int slot = atomicAdd(&cur[dn], 1);
        esrc[slot] = src[e];
        ews[slot] = w[e];
    }
}

// ---------------- fused per-node transformer ----------------
// grid 5000 x 256 threads; wave w handles node n = blockIdx*4+w; lane = feature d
__global__ void k_transformer(const float* __restrict__ x_seq,
                              const float* __restrict__ Wpi, const float* __restrict__ bpi,
                              const float* __restrict__ WqT, const float* __restrict__ bq,
                              const float* __restrict__ WkT, const float* __restrict__ bk,
                              const float* __restrict__ WvT, const float* __restrict__ bv,
                              const float* __restrict__ WoT, const float* __restrict__ bo,
                              const float* __restrict__ g1, const float* __restrict__ be1,
                              const float* __restrict__ W1T, const float* __restrict__ b1,
                              const float* __restrict__ W2T, const float* __restrict__ b2,
                              const float* __restrict__ g2, const float* __restrict__ be2,
                              const float* __restrict__ Wpo, const float* __restrict__ bpo,
                              float* __restrict__ XS) {
    __shared__ __align__(16) float sX[4][TT][68];
    __shared__ __align__(16) float sQ[4][TT][68];
    __shared__ __align__(16) float sK[4][TT][68];
    __shared__ __align__(16) float sV[4][TT][68];
    const int wid = threadIdx.x >> 6;
    const int d = threadIdx.x & 63;
    const int n = blockIdx.x * 4 + wid;

    // ---- input projection (F=1 -> outer product) ----
    float xr[TT];
    {
        float wpid = Wpi[d], bpid = bpi[d];
#pragma unroll
        for (int t = 0; t < TT; ++t) {
            float s = x_seq[t * NN + n];
            xr[t] = fmaf(s, wpid, bpid);
            sX[wid][t][d] = xr[t];
        }
    }
    __syncthreads();

    // ---- QKV ----
    float qa[TT], ka[TT], va[TT];
    {
        float b_q = bq[d], b_k = bk[d], b_v = bv[d];
#pragma unroll
        for (int t = 0; t < TT; ++t) { qa[t] = b_q; ka[t] = b_k; va[t] = b_v; }
    }
    for (int dd0 = 0; dd0 < 64; dd0 += 4) {
        float4 wq = *(const float4*)(WqT + d * 64 + dd0);
        float4 wk = *(const float4*)(WkT + d * 64 + dd0);
        float4 wv = *(const float4*)(WvT + d * 64 + dd0);
#pragma unroll
        for (int t = 0; t < TT; ++t) {
            float4 xv = *(const float4*)(&sX[wid][t][dd0]);
            qa[t] += dot4(xv, wq);
            ka[t] += dot4(xv, wk);
            va[t] += dot4(xv, wv);
        }
    }
#pragma unroll
    for (int t = 0; t < TT; ++t) {
        sQ[wid][t][d] = qa[t];
        sK[wid][t][d] = ka[t];
        sV[wid][t][d] = va[t];
    }
    __syncthreads();

    // ---- attention: lane = (head h, query row i) ----
    {
        const int hh = d >> 4;
        const int qi = d & 15;
        if (qi < TT) {
            const float* qr = &sQ[wid][qi][hh * 16];
            float4 q0 = *(const float4*)(qr);
            float4 q1 = *(const float4*)(qr + 4);
            float4 q2 = *(const float4*)(qr + 8);
            float4 q3 = *(const float4*)(qr + 12);
            float attp[TT];
            float mx = -1e30f;
#pragma unroll
            for (int j = 0; j < TT; ++j) {
                const float* kr = &sK[wid][j][hh * 16];
                float s = dot4(q0, *(const float4*)(kr)) +
                          dot4(q1, *(const float4*)(kr + 4)) +
                          dot4(q2, *(const float4*)(kr + 8)) +
                          dot4(q3, *(const float4*)(kr + 12));
                s *= 0.25f;  // 1/sqrt(16)
                attp[j] = s;
                mx = fmaxf(mx, s);
            }
            float ssum = 0.f;
#pragma unroll
            for (int j = 0; j < TT; ++j) { attp[j] = __expf(attp[j] - mx); ssum += attp[j]; }
            float inv = 1.0f / ssum;
            float4 a0 = {0, 0, 0, 0}, a1 = {0, 0, 0, 0}, a2 = {0, 0, 0, 0}, a3 = {0, 0, 0, 0};
#pragma unroll
            for (int j = 0; j < TT; ++j) {
                float p = attp[j] * inv;
                const float* vr = &sV[wid][j][hh * 16];
                float4 v0 = *(const float4*)(vr);
                float4 v1 = *(const float4*)(vr + 4);
                float4 v2 = *(const float4*)(vr + 8);
                float4 v3 = *(const float4*)(vr + 12);
                a0.x += p * v0.x; a0.y += p * v0.y; a0.z += p * v0.z; a0.w += p * v0.w;
                a1.x += p * v1.x; a1.y += p * v1.y; a1.z += p * v1.z; a1.w += p * v1.w;
                a2.x += p * v2.x; a2.y += p * v2.y; a2.z += p * v2.z; a2.w += p * v2.w;
                a3.x += p * v3.x; a3.y += p * v3.y; a3.z += p * v3.z; a3.w += p * v3.w;
            }
            float* ar = &sQ[wid][qi][hh * 16];   // reuse Q buffer as attention output
            *(float4*)(ar) = a0;
            *(float4*)(ar + 4) = a1;
            *(float4*)(ar + 8) = a2;
            *(float4*)(ar + 12) = a3;
        }
    }
    __syncthreads();

    // ---- Wo + residual + LN1 ----
    float x1r[TT];
    {
        float oa[TT];
        float b_o = bo[d];
#pragma unroll
        for (int t = 0; t < TT; ++t) oa[t] = b_o;
        for (int dd0 = 0; dd0 < 64; dd0 += 4) {
            float4 wo = *(const float4*)(WoT + d * 64 + dd0);
#pragma unroll
            for (int t = 0; t < TT; ++t) {
                float4 av = *(const float4*)(&sQ[wid][t][dd0]);
                oa[t] += dot4(av, wo);
            }
        }
        float g1d = g1[d], be1d = be1[d];
        const float inv64 = 1.0f / 64.0f;
#pragma unroll
        for (int t = 0; t < TT; ++t) {
            float y = xr[t] + oa[t];
            float s = wsum64(y);
            float s2 = wsum64(y * y);
            float m = s * inv64;
            float var = s2 * inv64 - m * m;
            x1r[t] = (y - m) * rsqrtf(var + 1e-5f) * g1d + be1d;
        }
    }
#pragma unroll
    for (int t = 0; t < TT; ++t) sX[wid][t][d] = x1r[t];
    __syncthreads();

    // ---- FFN: 64 -> 256 (relu) -> 64, chunked over 4 column groups ----
    float y2[TT];
    {
        float b2d = b2[d];
#pragma unroll
        for (int t = 0; t < TT; ++t) y2[t] = b2d;
    }
    for (int jj = 0; jj < 4; ++jj) {
        int j = jj * 64 + d;
        float hbuf[TT];
        float b1j = b1[j];
#pragma unroll
        for (int t = 0; t < TT; ++t) hbuf[t] = b1j;
        for (int dd0 = 0; dd0 < 64; dd0 += 4) {
            float4 w1 = *(const float4*)(W1T + j * 64 + dd0);
#pragma unroll
            for (int t = 0; t < TT; ++t) {
                float4 xv = *(const float4*)(&sX[wid][t][dd0]);
                hbuf[t] += dot4(xv, w1);
            }
        }
        __syncthreads();   // previous chunk's sK reads complete
#pragma unroll
        for (int t = 0; t < TT; ++t) sK[wid][t][d] = fmaxf(hbuf[t], 0.0f);
        __syncthreads();
        for (int dd0 = 0; dd0 < 64; dd0 += 4) {
            float4 w2 = *(const float4*)(W2T + d * 256 + jj * 64 + dd0);
#pragma unroll
            for (int t = 0; t < TT; ++t) {
                float4 hv = *(const float4*)(&sK[wid][t][dd0]);
                y2[t] += dot4(hv, w2);
            }
        }
    }

    // ---- LN2 + output projection (D -> 1) ----
    {
        float g2d = g2[d], be2d = be2[d], wpod = Wpo[d];
        float bpo0 = bpo[0];
        const float inv64 = 1.0f / 64.0f;
#pragma unroll
        for (int t = 0; t < TT; ++t) {
            float y = x1r[t] + y2[t];
            float s = wsum64(y);
            float s2 = wsum64(y * y);
            float m = s * inv64;
            float var = s2 * inv64 - m * m;
            float x2 = (y - m) * rsqrtf(var + 1e-5f) * g2d + be2d;
            float p = wsum64(x2 * wpod);
            if (d == 0) XS[t * NN + n] = p + bpo0;
        }
    }
}

// ---------------- GRU step kernel A: z, r gates ----------------
__global__ void k_gru_a(const float* __restrict__ XS, int tstep,
                        const float* __restrict__ h,
                        const int* __restrict__ offs, const int* __restrict__ esrc,
                        const float* __restrict__ ews,
                        const float* __restrict__ Az, const float* __restrict__ Bz,
                        const float* __restrict__ bz,
                        const float* __restrict__ CzT, const float* __restrict__ DzT,
                        const float* __restrict__ cz,
                        const float* __restrict__ Ar, const float* __restrict__ Br,
                        const float* __restrict__ br,
                        const float* __restrict__ CrT, const float* __restrict__ DrT,
                        const float* __restrict__ cr,
                        float* __restrict__ zb, float* __restrict__ rh) {
    __shared__ __align__(16) float Hs[4][68];
    __shared__ __align__(16) float Ms[4][68];
    const int wid = threadIdx.x >> 6;
    const int d = threadIdx.x & 63;
    const int n = blockIdx.x * 4 + wid;
    const float* xs_t = XS + tstep * NN;

    int beg = offs[n], end = offs[n + 1];
    float mh = 0.f, mx = 0.f;
    for (int i = beg; i < end; ++i) {
        int s = esrc[i];
        float w = ews[i];
        mh = fmaf(w, h[s * 64 + d], mh);
        mx = fmaf(w, xs_t[s], mx);
    }
    float hn = h[n * 64 + d];
    float xt = xs_t[n];
    Hs[wid][d] = hn;
    Ms[wid][d] = mh;
    __syncthreads();

    float zacc = xt * Az[d] + mx * Bz[d] + bz[d] + cz[d];
    float racc = xt * Ar[d] + mx * Br[d] + br[d] + cr[d];
    for (int k0 = 0; k0 < 64; k0 += 4) {
        float4 h4 = *(const float4*)(&Hs[wid][k0]);
        float4 m4 = *(const float4*)(&Ms[wid][k0]);
        float4 a = *(const float4*)(CzT + d * 64 + k0);
        float4 b = *(const float4*)(DzT + d * 64 + k0);
        float4 c = *(const float4*)(CrT + d * 64 + k0);
        float4 e = *(const float4*)(DrT + d * 64 + k0);
        zacc += dot4(h4, a) + dot4(m4, b);
        racc += dot4(h4, c) + dot4(m4, e);
    }
    float z = 1.0f / (1.0f + __expf(-zacc));
    float r = 1.0f / (1.0f + __expf(-racc));
    zb[n * 64 + d] = z;
    rh[n * 64 + d] = r * hn;
}

// ---------------- GRU step kernel B: candidate + h update (+ head on last step) ----------------
__global__ void k_gru_b(const float* __restrict__ XS, int tstep,
                        float* __restrict__ h,
                        const float* __restrict__ zb, const float* __restrict__ rh,
                        const int* __restrict__ offs, const int* __restrict__ esrc,
                        const float* __restrict__ ews,
                        const float* __restrict__ Ah, const float* __restrict__ Bh,
                        const float* __restrict__ bg,
                        const float* __restrict__ ChT, const float* __restrict__ DhT,
                        const float* __restrict__ cg,
                        const float* __restrict__ Whd, const float* __restrict__ bhd,
                        float* __restrict__ out, int last) {
    __shared__ __align__(16) float Rs[4][68];
    __shared__ __align__(16) float Ms[4][68];
    const int wid = threadIdx.x >> 6;
    const int d = threadIdx.x & 63;
    const int n = blockIdx.x * 4 + wid;
    const float* xs_t = XS + tstep * NN;

    int beg = offs[n], end = offs[n + 1];
    float mrh = 0.f, mx = 0.f;
    for (int i = beg; i < end; ++i) {
        int s = esrc[i];
        float w = ews[i];
        mrh = fmaf(w, rh[s * 64 + d], mrh);
        mx = fmaf(w, xs_t[s], mx);
    }
    float rhn = rh[n * 64 + d];
    float xt = xs_t[n];
    Rs[wid][d] = rhn;
    Ms[wid][d] = mrh;
    __syncthreads();

    float gacc = xt * Ah[d] + mx * Bh[d] + bg[d] + cg[d];
    for (int k0 = 0; k0 < 64; k0 += 4) {
        float4 r4 = *(const float4*)(&Rs[wid][k0]);
        float4 m4 = *(const float4*)(&Ms[wid][k0]);
        float4 a = *(const float4*)(ChT + d * 64 + k0);
        float4 b = *(const float4*)(DhT + d * 64 + k0);
        gacc += dot4(r4, a) + dot4(m4, b);
    }
    float g = tanhf(gacc);
    float z = zb[n * 64 + d];
    float hn = h[n * 64 + d];
    float hnew = z * hn + (1.0f - z) * g;
    h[n * 64 + d] = hnew;

    if (last) {
        float p = fmaxf(hnew, 0.0f) * Whd[d];
        float s = wsum64(p);
        if (d == 0) out[n] = s + bhd[0];
    }
}

extern "C" void kernel_launch(void* const* d_in, const int* in_sizes, int n_in,
                              void* d_out, int out_size, void* d_ws, size_t ws_size,
                              hipStream_t stream) {
    const float* x_seq = (const float*)d_in[0];
    const int* eidx = (const int*)d_in[1];
    const float* ew = (const float*)d_in[2];
    const float* Wpi = (const float*)d_in[3];
    const float* bpi = (const float*)d_in[4];
    const float* Wq = (const float*)d_in[5];
    const float* Wk = (const float*)d_in[6];
    const float* Wv = (const float*)d_in[7];
    const float* Wo = (const float*)d_in[8];
    const float* W1 = (const float*)d_in[9];
    const float* W2 = (const float*)d_in[10];
    const float* Wpo = (const float*)d_in[11];
    const float* bq = (const float*)d_in[12];
    const float* bk = (const float*)d_in[13];
    const float* bv = (const float*)d_in[14];
    const float* bo = (const float*)d_in[15];
    const float* b1 = (const float*)d_in[16];
    const float* b2 = (const float*)d_in[17];
    const float* bpo = (const float*)d_in[18];
    const float* g1 = (const float*)d_in[19];
    const float* be1 = (const float*)d_in[20];
    const float* g2 = (const float*)d_in[21];
    const float* be2 = (const float*)d_in[22];
    const float* Az = (const float*)d_in[23];
    const float* Bz = (const float*)d_in[24];
    const float* bz = (const float*)d_in[25];
    const float* Cz = (const float*)d_in[26];
    const float* Dz = (const float*)d_in[27];
    const float* cz = (const float*)d_in[28];
    const float* Ar = (const float*)d_in[29];
    const float* Br = (const float*)d_in[30];
    const float* br_ = (const float*)d_in[31];
    const float* Cr = (const float*)d_in[32];
    const float* Dr = (const float*)d_in[33];
    const float* cr_ = (const float*)d_in[34];
    const float* Ah = (const float*)d_in[35];
    const float* Bh = (const float*)d_in[36];
    const float* bg = (const float*)d_in[37];
    const float* Ch = (const float*)d_in[38];
    const float* Dh = (const float*)d_in[39];
    const float* cg = (const float*)d_in[40];
    const float* Whd = (const float*)d_in[41];
    const float* bhd = (const float*)d_in[42];

    float* ws = (float*)d_ws;
    float* XS = ws;                         // 240000
    float* hbuf = XS + 240000;              // 1280000
    float* rhbuf = hbuf + 1280000;          // 1280000
    float* zbuf = rhbuf + 1280000;          // 1280000
    float* WT = zbuf + 1280000;             // 73728
    const float* WqT = WT + 0;
    const float* WkT = WT + 4096;
    const float* WvT = WT + 8192;
    const float* WoT = WT + 12288;
    const float* CzT = WT + 16384;
    const float* DzT = WT + 20480;
    const float* CrT = WT + 24576;
    const float* DrT = WT + 28672;
    const float* ChT = WT + 32768;
    const float* DhT = WT + 36864;
    const float* W1T = WT + 40960;
    const float* W2T = WT + 57344;
    int* ioffs = (int*)(WT + 73728);        // NN+1
    int* cur = ioffs + (NN + 1);            // NN
    int* esrc = cur + NN;                   // EE
    float* ews = (float*)(esrc + EE);       // EE

    const int* e_src = eidx;
    const int* e_dst = eidx + EE;

    hipMemsetAsync(hbuf, 0, (size_t)NN * 64 * sizeof(float), stream);
    k_transpose<<<288, 256, 0, stream>>>(Wq, Wk, Wv, Wo, Cz, Dz, Cr, Dr, Ch, Dh, W1, W2, WT);
    k_zero_offs<<<(NN + 1 + 255) / 256, 256, 0, stream>>>(ioffs);
    k_count<<<(EE + 255) / 256, 256, 0, stream>>>(e_dst, ioffs);
    k_scan<<<1, 1024, 0, stream>>>(ioffs, cur);
    k_fill<<<(EE + 255) / 256, 256, 0, stream>>>(e_src, e_dst, ew, cur, esrc, ews);

    k_transformer<<<5000, 256, 0, stream>>>(x_seq, Wpi, bpi, WqT, bq, WkT, bk, WvT, bv,
                                            WoT, bo, g1, be1, W1T, b1, W2T, b2, g2, be2,
                                            Wpo, bpo, XS);

    for (int t = 0; t < TT; ++t) {
        k_gru_a<<<5000, 256, 0, stream>>>(XS, t, hbuf, ioffs, esrc, ews,
                                          Az, Bz, bz, CzT, DzT, cz,
                                          Ar, Br, br_, CrT, DrT, cr_,
                                          zbuf, rhbuf);
        k_gru_b<<<5000, 256, 0, stream>>>(XS, t, hbuf, zbuf, rhbuf, ioffs, esrc, ews,
                                          Ah, Bh, bg, ChT, DhT, cg,
                                          Whd, bhd, (float*)d_out, (t == TT - 1) ? 1 : 0);
    }
}